// Round 1
// baseline (464.045 us; speedup 1.0000x reference)
//
#include <hip/hip_runtime.h>
#include <hip/hip_bf16.h>
#include <math.h>

// ---------------------------------------------------------------------------
// GPT block on MI355X (gfx950). bf16 MFMA compute, fp32 accumulate.
// Workspace layout (bytes, MB = 1<<20), total 72 MB:
//   [ 0, 2)  WtQ   bf16 [1024][1024]   (W_Q transposed, bf16)
//   [ 2, 4)  WtK
//   [ 4, 6)  WtV
//   [ 6, 8)  WtO
//   [ 8,16)  Wtfc  bf16 [4096][1024]
//   [16,24)  Wtproj bf16 [1024][4096]
//   [24,32)  zn / ctx   bf16 [4096][1024]   (zn dead after QKV -> reused as ctx)
//   [32,40)  Q / h      bf16 [4096][1024]   (Q dead after attn -> reused as h)
//   [40,48)  K          bf16 [4096][1024]
//   [48,56)  V          bf16 [4096][1024]
//   [40,72)  ffn1       bf16 [4096][4096]   (overlaps K,V which are dead by then)
// d_out doubles as z2 (fp32): O-proj writes z2 = z + attn; proj does +=.
// ---------------------------------------------------------------------------

typedef __bf16 bf16x8 __attribute__((ext_vector_type(8)));
typedef float  f32x4  __attribute__((ext_vector_type(4)));
typedef unsigned short u16x8 __attribute__((ext_vector_type(8)));

#define MFMA_16x16x32_BF16(A, B, C) __builtin_amdgcn_mfma_f32_16x16x32_bf16((A), (B), (C), 0, 0, 0)

// ---------------- transpose + fp32->bf16 convert:  src[K][N] -> dst[N][K] ----
__global__ __launch_bounds__(256) void transconv_kernel(
    const float* __restrict__ src, __bf16* __restrict__ dst, int K, int N)
{
    __shared__ float tile[32][33];
    const int n0 = blockIdx.x * 32, k0 = blockIdx.y * 32;
    const int c = threadIdx.x & 31, r = threadIdx.x >> 5;  // 8 rows per pass
#pragma unroll
    for (int i = 0; i < 4; ++i)
        tile[r + 8 * i][c] = src[(size_t)(k0 + r + 8 * i) * N + n0 + c];
    __syncthreads();
#pragma unroll
    for (int i = 0; i < 4; ++i)
        dst[(size_t)(n0 + r + 8 * i) * K + k0 + c] = (__bf16)tile[c][r + 8 * i];
}

// ---------------- RMSNorm: fp32 [M][1024] -> bf16 [M][1024] -----------------
__global__ __launch_bounds__(256) void rmsnorm_kernel(
    const float* __restrict__ x, const float* __restrict__ gain,
    __bf16* __restrict__ out)
{
    const int row = blockIdx.x, t = threadIdx.x;
    const float4 v = ((const float4*)(x + (size_t)row * 1024))[t];
    float ss = v.x * v.x + v.y * v.y + v.z * v.z + v.w * v.w;
#pragma unroll
    for (int m = 1; m < 64; m <<= 1) ss += __shfl_xor(ss, m);
    __shared__ float red[4];
    const int wid = t >> 6, lane = t & 63;
    if (lane == 0) red[wid] = ss;
    __syncthreads();
    const float tot = red[0] + red[1] + red[2] + red[3];
    const float inv = rsqrtf(tot * (1.0f / 1024.0f) + 1e-5f);
    const float4 gv = ((const float4*)gain)[t];
    __bf16* o = out + (size_t)row * 1024 + t * 4;
    o[0] = (__bf16)(v.x * inv * gv.x);
    o[1] = (__bf16)(v.y * inv * gv.y);
    o[2] = (__bf16)(v.z * inv * gv.z);
    o[3] = (__bf16)(v.w * inv * gv.w);
}

// ---------------- GEMM: C[M][N] = A[M][K] * Bt[N][K]^T, bf16 MFMA ----------
// EPI: 0 = store bf16; 1 = out_f32 = res + acc; 2 = store bf16 gelu_erf(acc);
//      3 = out_f32 += acc
#define LDT 72
template <int EPI>
__global__ __launch_bounds__(256) void gemm_bf16(
    const __bf16* __restrict__ A, const __bf16* __restrict__ Bt,
    void* __restrict__ outp, const float* __restrict__ res,
    int M, int N, int K)
{
    __shared__ __bf16 As[128 * LDT];
    __shared__ __bf16 Bs[128 * LDT];
    const int tid = threadIdx.x;
    const int m0 = blockIdx.y * 128, n0 = blockIdx.x * 128;
    const int lane = tid & 63, w = tid >> 6;
    const int wm = w >> 1, wn = w & 1;
    const int lr = lane & 15, g = lane >> 4;
    const int cc = (tid & 7) * 8, rr = tid >> 3;  // stage: 8 chunks/row, 32 rows/pass

    f32x4 acc[4][4] = {};

    for (int kb = 0; kb < K; kb += 64) {
#pragma unroll
        for (int i = 0; i < 4; ++i) {
            const int row = rr + 32 * i;
            *(u16x8*)&As[row * LDT + cc] =
                *(const u16x8*)&A[(size_t)(m0 + row) * K + kb + cc];
            *(u16x8*)&Bs[row * LDT + cc] =
                *(const u16x8*)&Bt[(size_t)(n0 + row) * K + kb + cc];
        }
        __syncthreads();

        bf16x8 af[2][4], bf[2][4];
#pragma unroll
        for (int kk = 0; kk < 2; ++kk)
#pragma unroll
            for (int i = 0; i < 4; ++i) {
                af[kk][i] = *(const bf16x8*)&As[(wm * 64 + i * 16 + lr) * LDT + kk * 32 + g * 8];
                bf[kk][i] = *(const bf16x8*)&Bs[(wn * 64 + i * 16 + lr) * LDT + kk * 32 + g * 8];
            }
#pragma unroll
        for (int kk = 0; kk < 2; ++kk)
#pragma unroll
            for (int mi = 0; mi < 4; ++mi)
#pragma unroll
                for (int ni = 0; ni < 4; ++ni)
                    acc[mi][ni] = MFMA_16x16x32_BF16(af[kk][mi], bf[kk][ni], acc[mi][ni]);
        __syncthreads();
    }

#pragma unroll
    for (int mi = 0; mi < 4; ++mi)
#pragma unroll
        for (int ni = 0; ni < 4; ++ni) {
            const int colg = n0 + wn * 64 + ni * 16 + lr;
#pragma unroll
            for (int r = 0; r < 4; ++r) {
                const int rowg = m0 + wm * 64 + mi * 16 + 4 * g + r;
                const size_t idx = (size_t)rowg * N + colg;
                const float v = acc[mi][ni][r];
                if constexpr (EPI == 0) {
                    ((__bf16*)outp)[idx] = (__bf16)v;
                } else if constexpr (EPI == 1) {
                    ((float*)outp)[idx] = res[idx] + v;
                } else if constexpr (EPI == 2) {
                    ((__bf16*)outp)[idx] =
                        (__bf16)(0.5f * v * (1.0f + erff(v * 0.70710678118654752f)));
                } else {
                    ((float*)outp)[idx] += v;
                }
            }
        }
}

// ---------------- Flash-style causal attention ------------------------------
// One wave per 16 query rows. Swapped QK^T: S^T = K·Q^T so P is directly the
// PV A-fragment. dh = 64, kv steps of 32 (two 16-row S^T tiles per step).
__global__ __launch_bounds__(256) void attn_kernel(
    const __bf16* __restrict__ Q, const __bf16* __restrict__ Kb,
    const __bf16* __restrict__ Vb, __bf16* __restrict__ ctx)
{
    const int Dm = 1024, T = 2048;
    const int tid = threadIdx.x;
    const int w = tid >> 6, lane = tid & 63;
    const int lr = lane & 15, g = lane >> 4;
    const int blk = blockIdx.x;
    const int qc = blk & 31, h = (blk >> 5) & 15, b = blk >> 9;
    const int qbase = qc * 64 + w * 16;
    const size_t rowoff = (size_t)b * T;
    const __bf16* Qp = Q + rowoff * Dm + h * 64;
    const __bf16* Kp = Kb + rowoff * Dm + h * 64;
    const __bf16* Vp = Vb + rowoff * Dm + h * 64;

    const bf16x8 qf0 = *(const bf16x8*)&Qp[(size_t)(qbase + lr) * Dm + g * 8];
    const bf16x8 qf1 = *(const bf16x8*)&Qp[(size_t)(qbase + lr) * Dm + 32 + g * 8];

    f32x4 acc[4] = {};
    float m_s = -__builtin_inff(), l_s = 0.0f;

    const int nsteps = (qbase + 16 + 31) >> 5;
    for (int s = 0; s < nsteps; ++s) {
        const int kvb = s * 32;
        const __bf16* k0p = &Kp[(size_t)(kvb + lr) * Dm];
        const __bf16* k1p = &Kp[(size_t)(kvb + 16 + lr) * Dm];
        const bf16x8 kf0a = *(const bf16x8*)&k0p[g * 8];
        const bf16x8 kf0b = *(const bf16x8*)&k0p[32 + g * 8];
        const bf16x8 kf1a = *(const bf16x8*)&k1p[g * 8];
        const bf16x8 kf1b = *(const bf16x8*)&k1p[32 + g * 8];

        const f32x4 zacc = {0.0f, 0.0f, 0.0f, 0.0f};
        f32x4 st0 = MFMA_16x16x32_BF16(kf0a, qf0, zacc);
        st0 = MFMA_16x16x32_BF16(kf0b, qf1, st0);
        f32x4 st1 = MFMA_16x16x32_BF16(kf1a, qf0, zacc);
        st1 = MFMA_16x16x32_BF16(kf1b, qf1, st1);

        const int qg = qbase + lr;
        const bool domask = (kvb + 31 > qbase);
        float s0[4], s1[4];
#pragma unroll
        for (int r = 0; r < 4; ++r) {
            const int kv0 = kvb + 4 * g + r;
            s0[r] = st0[r] * 0.125f;
            s1[r] = st1[r] * 0.125f;
            if (domask) {
                if (kv0 > qg) s0[r] = -__builtin_inff();
                if (kv0 + 16 > qg) s1[r] = -__builtin_inff();
            }
        }
        float tm = fmaxf(fmaxf(fmaxf(s0[0], s0[1]), fmaxf(s0[2], s0[3])),
                         fmaxf(fmaxf(s1[0], s1[1]), fmaxf(s1[2], s1[3])));
        tm = fmaxf(tm, __shfl_xor(tm, 16));
        tm = fmaxf(tm, __shfl_xor(tm, 32));
        const float m_new = fmaxf(m_s, tm);
        const float corr = __expf(m_s - m_new);
        float p0[4], p1[4], rs = 0.0f;
#pragma unroll
        for (int r = 0; r < 4; ++r) {
            p0[r] = __expf(s0[r] - m_new);
            p1[r] = __expf(s1[r] - m_new);
            rs += p0[r] + p1[r];
        }
        rs += __shfl_xor(rs, 16);
        rs += __shfl_xor(rs, 32);
        l_s = l_s * corr + rs;
        m_s = m_new;

        float cr[4];
#pragma unroll
        for (int r = 0; r < 4; ++r) cr[r] = __shfl(corr, 4 * g + r);
#pragma unroll
        for (int ct = 0; ct < 4; ++ct) {
            acc[ct][0] *= cr[0]; acc[ct][1] *= cr[1];
            acc[ct][2] *= cr[2]; acc[ct][3] *= cr[3];
        }

        bf16x8 pa;
#pragma unroll
        for (int r = 0; r < 4; ++r) {
            pa[r] = (__bf16)p0[r];
            pa[4 + r] = (__bf16)p1[r];
        }
#pragma unroll
        for (int ct = 0; ct < 4; ++ct) {
            const __bf16* vc = &Vp[ct * 16 + lr];
            bf16x8 vf;
#pragma unroll
            for (int j = 0; j < 4; ++j) {
                vf[j]     = vc[(size_t)(kvb + 4 * g + j) * Dm];
                vf[4 + j] = vc[(size_t)(kvb + 16 + 4 * g + j) * Dm];
            }
            acc[ct] = MFMA_16x16x32_BF16(pa, vf, acc[ct]);
        }
    }

    float dn[4];
#pragma unroll
    for (int r = 0; r < 4; ++r) dn[r] = __shfl(l_s, 4 * g + r);
#pragma unroll
    for (int ct = 0; ct < 4; ++ct)
#pragma unroll
        for (int r = 0; r < 4; ++r)
            ctx[(rowoff + qbase + 4 * g + r) * Dm + h * 64 + ct * 16 + lr] =
                (__bf16)(acc[ct][r] / dn[r]);
}

// ---------------------------------------------------------------------------
extern "C" void kernel_launch(void* const* d_in, const int* in_sizes, int n_in,
                              void* d_out, int out_size, void* d_ws, size_t ws_size,
                              hipStream_t stream)
{
    (void)in_sizes; (void)n_in; (void)out_size; (void)ws_size;
    const float* z      = (const float*)d_in[0];
    const float* W_Q    = (const float*)d_in[1];
    const float* W_K    = (const float*)d_in[2];
    const float* W_V    = (const float*)d_in[3];
    const float* W_O    = (const float*)d_in[4];
    const float* W_fc   = (const float*)d_in[5];
    const float* W_proj = (const float*)d_in[6];
    const float* g1     = (const float*)d_in[7];
    const float* g2     = (const float*)d_in[8];
    float* out = (float*)d_out;

    char* ws = (char*)d_ws;
    const size_t MB = (size_t)1 << 20;
    __bf16* WtQ    = (__bf16*)(ws + 0 * MB);
    __bf16* WtK    = (__bf16*)(ws + 2 * MB);
    __bf16* WtV    = (__bf16*)(ws + 4 * MB);
    __bf16* WtO    = (__bf16*)(ws + 6 * MB);
    __bf16* Wtfc   = (__bf16*)(ws + 8 * MB);
    __bf16* Wtproj = (__bf16*)(ws + 16 * MB);
    __bf16* zn     = (__bf16*)(ws + 24 * MB);  // reused as ctx
    __bf16* Qb     = (__bf16*)(ws + 32 * MB);  // reused as h
    __bf16* Kbuf   = (__bf16*)(ws + 40 * MB);
    __bf16* Vbuf   = (__bf16*)(ws + 48 * MB);
    __bf16* ffn1   = (__bf16*)(ws + 40 * MB);  // overlaps K,V (dead by then)
    __bf16* ctx    = zn;
    __bf16* hb     = Qb;

    const int Tt = 2048, Dm = 1024, Bb = 2, M = Bb * Tt, DFF = 4096;
    const dim3 blk256(256);

    // Weight transpose+convert
    transconv_kernel<<<dim3(32, 32),  blk256, 0, stream>>>(W_Q, WtQ, Dm, Dm);
    transconv_kernel<<<dim3(32, 32),  blk256, 0, stream>>>(W_K, WtK, Dm, Dm);
    transconv_kernel<<<dim3(32, 32),  blk256, 0, stream>>>(W_V, WtV, Dm, Dm);
    transconv_kernel<<<dim3(32, 32),  blk256, 0, stream>>>(W_O, WtO, Dm, Dm);
    transconv_kernel<<<dim3(128, 32), blk256, 0, stream>>>(W_fc, Wtfc, Dm, DFF);
    transconv_kernel<<<dim3(32, 128), blk256, 0, stream>>>(W_proj, Wtproj, DFF, Dm);

    // zn = rmsnorm(z, g1)
    rmsnorm_kernel<<<M, blk256, 0, stream>>>(z, g1, zn);

    // Q, K, V
    gemm_bf16<0><<<dim3(8, 32), blk256, 0, stream>>>(zn, WtQ, Qb,   nullptr, M, Dm, Dm);
    gemm_bf16<0><<<dim3(8, 32), blk256, 0, stream>>>(zn, WtK, Kbuf, nullptr, M, Dm, Dm);
    gemm_bf16<0><<<dim3(8, 32), blk256, 0, stream>>>(zn, WtV, Vbuf, nullptr, M, Dm, Dm);

    // attention -> ctx
    attn_kernel<<<1024, blk256, 0, stream>>>(Qb, Kbuf, Vbuf, ctx);

    // z2 = z + ctx @ W_O   -> d_out (fp32)
    gemm_bf16<1><<<dim3(8, 32), blk256, 0, stream>>>(ctx, WtO, out, z, M, Dm, Dm);

    // h = rmsnorm(z2, g2)
    rmsnorm_kernel<<<M, blk256, 0, stream>>>(out, g2, hb);

    // ffn1 = gelu_erf(h @ W_fc)
    gemm_bf16<2><<<dim3(32, 32), blk256, 0, stream>>>(hb, Wtfc, ffn1, nullptr, M, DFF, Dm);

    // d_out += ffn1 @ W_proj
    gemm_bf16<3><<<dim3(8, 32), blk256, 0, stream>>>(ffn1, Wtproj, out, nullptr, M, Dm, DFF);
}